// Round 3
// baseline (810.679 us; speedup 1.0000x reference)
//
#include <hip/hip_runtime.h>
#include <hip/hip_bf16.h>

// MultimodalFusion: B=16384, S=3, D=512, H=8, HD=64, FF=2048
// Round 3: pipelined GEMM K-loop — BK=32 double-buffered LDS staged via
// global_load_lds, raw s_barrier + manual s_waitcnt vmcnt(4) so prefetch
// loads stay in flight across barriers (never vmcnt(0) mid-loop).
// Residual adds fused into GEMM epilogues:
//   out-proj: y' = x + o@w_out^T + b      (reads xbf in epilogue)
//   FFN2:     f' = x1 + h@w2^T + b2       (reads x1 in epilogue)
// so ln1 reads only y' and final_k reads only f'.
//
// Pipeline:
//   K0 cast weights fp32->bf16
//   K1 x = feat+pos -> bf16 [rows,512]            (xbf)
//   K2 GEMM qkv = x @ w_in^T + b_in -> bf16       (regB)
//   K3 attention per (b,head) wave -> bf16 o      (ob)
//   K4 GEMM y' = x + o @ w_out^T + b_out -> f32   (regB, res=xbf)
//   K5 x1 = LN1(y') -> bf16                       (xbf, overwrites x)
//   K6 GEMM h = relu(x1 @ w1^T + b1) -> bf16      (hb)
//   K7 GEMM f' = x1 + h @ w2^T + b2 -> f32        (regB, res=xbf)
//   K8 out[b] = mean_s LN2(f')

#define BTOT 16384
#define DD 512
#define EPS_ 1e-5f

typedef __attribute__((ext_vector_type(8))) short bf8v;
typedef __attribute__((ext_vector_type(4))) float f4v;

__device__ __forceinline__ unsigned short f2bf(float f) {
  unsigned int u = __builtin_bit_cast(unsigned int, f);
  u += 0x7fffu + ((u >> 16) & 1u);
  return (unsigned short)(u >> 16);
}
__device__ __forceinline__ float bf2f(unsigned short s) {
  unsigned int u = ((unsigned int)s) << 16;
  return __builtin_bit_cast(float, u);
}
__device__ __forceinline__ unsigned int pk2(float a, float b) {
  return (unsigned int)f2bf(a) | ((unsigned int)f2bf(b) << 16);
}

// async global->LDS, 16B per lane; lds dst is wave-uniform base + lane*16
#define GLDS16(gp, lp)                                                   \
  __builtin_amdgcn_global_load_lds(                                      \
      (const __attribute__((address_space(1))) void*)(gp),               \
      (__attribute__((address_space(3))) void*)(lp), 16, 0, 0)

// s_waitcnt immediates (gfx9 encoding): vm[3:0], exp[6:4]=7, lgkm[11:8]=0xF
#define WAIT_VM4 0x0F74
#define WAIT_VM0 0x0F70
#define CFENCE() __asm__ volatile("" ::: "memory")

// ---------------- K0: weight cast ----------------
__global__ __launch_bounds__(256) void cast_w(const float* __restrict__ w,
                                              unsigned short* __restrict__ o, int n) {
  int i = (blockIdx.x * 256 + threadIdx.x) * 4;
  if (i >= n) return;
  float4 v = *(const float4*)&w[i];
  uint2 u; u.x = pk2(v.x, v.y); u.y = pk2(v.z, v.w);
  *(uint2*)&o[i] = u;
}

// ---------------- K1: build x = feat + pos -> bf16 ----------------
__global__ __launch_bounds__(256) void build_x(const float* __restrict__ f0,
                                               const float* __restrict__ f1,
                                               const float* __restrict__ f2,
                                               const float* __restrict__ pos,
                                               unsigned short* __restrict__ xbf, int b0) {
  int gi = blockIdx.x * 256 + threadIdx.x;
  int e = gi * 4;
  int r = e >> 9;
  int d = e & 511;
  int bl = r / 3, s = r - bl * 3;
  const float* f = (s == 0 ? f0 : (s == 1 ? f1 : f2)) + (size_t)(b0 + bl) * DD + d;
  const float* pp = pos + s * DD + d;
  float4 fv = *(const float4*)f;
  float4 pv = *(const float4*)pp;
  uint2 o; o.x = pk2(fv.x + pv.x, fv.y + pv.y); o.y = pk2(fv.z + pv.z, fv.w + pv.w);
  *(uint2*)&xbf[(size_t)r * DD + d] = o;
}

// ---------------- GEMM: C[M,N] = A[M,K] @ Bw[N,K]^T + bias (+res) ---------
// 128x128 tile, 4 waves 2x2, wave = 4x4 of 16x16x32 MFMA. BK=32, dbuf LDS.
// LDS tile [128][32] bf16 (64 B rows). Chunk (8 bf16 = 16 B) q of row r is
// stored at slot q ^ ((r>>1)&3): fragment ds_read_b128 then lands 2 lanes
// per bank-quad (free); staging GLDS dst is lane-ordered so the swizzle is
// applied on the global address side: lane l fetches global chunk
// (l&3) ^ ((l>>3)&3) of row l>>2.
// Pipeline: prologue stages buf0(k=0), buf1(k=32); per iter: wait vmcnt(4)
// (current buf only; next buf's 4 loads stay in flight), s_barrier, compute,
// s_barrier, refill current buf for k+64.
#define TM 128
#define TN 128

template <int ACT, int OBF, int RES>
__global__ __launch_bounds__(256, 2) void gemm_bt(const unsigned short* __restrict__ A,
                                                  const unsigned short* __restrict__ Bw,
                                                  const float* __restrict__ bias,
                                                  const unsigned short* __restrict__ res,
                                                  void* __restrict__ C, int M, int N, int K) {
  __shared__ unsigned short lA[2][TM * 32];
  __shared__ unsigned short lB[2][TN * 32];
  const int tid = threadIdx.x;
  const int row0 = blockIdx.y * TM;
  const int col0 = blockIdx.x * TN;
  const int lane = tid & 63;
  const int w = tid >> 6;
  const int wm = (w >> 1) * 64;
  const int wn = (w & 1) * 64;
  const int lr = lane & 15;
  const int ql = lane >> 4;
  const int fslot = (ql ^ ((lr >> 1) & 3)) * 8;  // short offset within row

  f4v acc[4][4];
#pragma unroll
  for (int i = 0; i < 4; i++)
#pragma unroll
    for (int j = 0; j < 4; j++) acc[i][j] = (f4v)0.f;

  // staging geometry: wave w stages rows [w*32, w*32+32) of A and B
  const int srow = w * 32 + (lane >> 2);
  const int gq8 = (((lane & 3) ^ ((lane >> 3) & 3)) << 3);  // swizzled k-chunk (elems)
  const unsigned short* AgB = A + (size_t)(row0 + srow) * K + gq8;
  const unsigned short* BgB = Bw + (size_t)(col0 + srow) * K + gq8;
  const int lds0 = (w * 32) * 32;        // wave-uniform short index
  const int lds1 = (w * 32 + 16) * 32;

#define STAGE(buf, kk)                                  \
  {                                                     \
    GLDS16(AgB + (kk), &lA[buf][lds0]);                 \
    GLDS16(AgB + (size_t)16 * K + (kk), &lA[buf][lds1]);\
    GLDS16(BgB + (kk), &lB[buf][lds0]);                 \
    GLDS16(BgB + (size_t)16 * K + (kk), &lB[buf][lds1]);\
  }

  STAGE(0, 0)
  STAGE(1, 32)
  int cur = 0;

  for (int k0 = 0; k0 < K; k0 += 32) {
    CFENCE();
    if (k0 + 32 < K) __builtin_amdgcn_s_waitcnt(WAIT_VM4);
    else             __builtin_amdgcn_s_waitcnt(WAIT_VM0);
    __builtin_amdgcn_s_barrier();
    CFENCE();
    bf8v af[4], bfr[4];
#pragma unroll
    for (int i = 0; i < 4; i++)
      af[i] = *(const bf8v*)&lA[cur][(wm + i * 16 + lr) * 32 + fslot];
#pragma unroll
    for (int j = 0; j < 4; j++)
      bfr[j] = *(const bf8v*)&lB[cur][(wn + j * 16 + lr) * 32 + fslot];
#pragma unroll
    for (int i = 0; i < 4; i++)
#pragma unroll
      for (int j = 0; j < 4; j++)
        acc[i][j] = __builtin_amdgcn_mfma_f32_16x16x32_bf16(af[i], bfr[j], acc[i][j], 0, 0, 0);
    CFENCE();
    __builtin_amdgcn_s_barrier();
    CFENCE();
    if (k0 + 64 < K) STAGE(cur, k0 + 64)
    cur ^= 1;
  }
#undef STAGE

#pragma unroll
  for (int j = 0; j < 4; j++) {
    int gcol = col0 + wn + j * 16 + lr;
    float bv = bias[gcol];
#pragma unroll
    for (int i = 0; i < 4; i++) {
#pragma unroll
      for (int r = 0; r < 4; r++) {
        int grow = row0 + wm + i * 16 + (lane >> 4) * 4 + r;
        float v = acc[i][j][r] + bv;
        if (RES) v += bf2f(res[(size_t)grow * N + gcol]);
        if (ACT) v = fmaxf(v, 0.f);
        if (OBF)
          ((unsigned short*)C)[(size_t)grow * N + gcol] = f2bf(v);
        else
          ((float*)C)[(size_t)grow * N + gcol] = v;
      }
    }
  }
}

// ---------------- K3: attention, one wave per (b, head) ----------------
__global__ __launch_bounds__(512) void attn_k(const unsigned short* __restrict__ qkv,
                                              unsigned short* __restrict__ ob) {
  int b = blockIdx.x;
  int h = threadIdx.x >> 6;
  int lane = threadIdx.x & 63;
  size_t base = ((size_t)b * 3) * 1536 + h * 64 + lane;
  float q[3], k[3], v[3];
#pragma unroll
  for (int s = 0; s < 3; s++) {
    q[s] = bf2f(qkv[base + (size_t)s * 1536]);
    k[s] = bf2f(qkv[base + (size_t)s * 1536 + 512]);
    v[s] = bf2f(qkv[base + (size_t)s * 1536 + 1024]);
  }
  float sc[3][3];
#pragma unroll
  for (int qi = 0; qi < 3; qi++)
#pragma unroll
    for (int ki = 0; ki < 3; ki++) {
      float p = q[qi] * k[ki];
#pragma unroll
      for (int off = 32; off > 0; off >>= 1) p += __shfl_xor(p, off, 64);
      sc[qi][ki] = p * 0.125f;  // 1/sqrt(64)
    }
#pragma unroll
  for (int qi = 0; qi < 3; qi++) {
    float m = fmaxf(sc[qi][0], fmaxf(sc[qi][1], sc[qi][2]));
    float e0 = __expf(sc[qi][0] - m), e1 = __expf(sc[qi][1] - m), e2 = __expf(sc[qi][2] - m);
    float inv = 1.f / (e0 + e1 + e2);
    float o = (e0 * v[0] + e1 * v[1] + e2 * v[2]) * inv;
    ob[((size_t)b * 3 + qi) * DD + h * 64 + lane] = f2bf(o);
  }
}

// ---------------- K5: x1 = LN(y') -> bf16; one wave per row ----------------
__global__ __launch_bounds__(256) void ln_row(const float* __restrict__ y,
                                              const float* __restrict__ g,
                                              const float* __restrict__ be,
                                              unsigned short* __restrict__ xo) {
  int wid = threadIdx.x >> 6, lane = threadIdx.x & 63;
  size_t r = (size_t)blockIdx.x * 4 + wid;
  int d = lane * 8;
  float4 a = *(const float4*)&y[r * DD + d];
  float4 b = *(const float4*)&y[r * DD + d + 4];
  float x[8] = {a.x, a.y, a.z, a.w, b.x, b.y, b.z, b.w};
  float su = 0.f, sq = 0.f;
#pragma unroll
  for (int i = 0; i < 8; i++) { su += x[i]; sq += x[i] * x[i]; }
#pragma unroll
  for (int off = 32; off > 0; off >>= 1) {
    su += __shfl_xor(su, off, 64);
    sq += __shfl_xor(sq, off, 64);
  }
  float mean = su * (1.f / 512.f);
  float var = sq * (1.f / 512.f) - mean * mean;
  float rs = rsqrtf(var + EPS_);
  unsigned short o[8];
#pragma unroll
  for (int i = 0; i < 8; i++) o[i] = f2bf((x[i] - mean) * rs * g[d + i] + be[d + i]);
  uint4 pack;
  pack.x = (unsigned)o[0] | ((unsigned)o[1] << 16);
  pack.y = (unsigned)o[2] | ((unsigned)o[3] << 16);
  pack.z = (unsigned)o[4] | ((unsigned)o[5] << 16);
  pack.w = (unsigned)o[6] | ((unsigned)o[7] << 16);
  *(uint4*)&xo[r * DD + d] = pack;
}

// ---------------- K8: out[b] = mean_s LN2(f') ----------------
__global__ __launch_bounds__(192) void final_k(const float* __restrict__ ff,
                                               const float* __restrict__ g,
                                               const float* __restrict__ be,
                                               float* __restrict__ out) {
  __shared__ float t3[3][DD];
  int w = threadIdx.x >> 6, lane = threadIdx.x & 63;
  int b = blockIdx.x;
  size_t r = (size_t)b * 3 + w;
  int d = lane * 8;
  float4 a = *(const float4*)&ff[r * DD + d];
  float4 bb = *(const float4*)&ff[r * DD + d + 4];
  float x[8] = {a.x, a.y, a.z, a.w, bb.x, bb.y, bb.z, bb.w};
  float su = 0.f, sq = 0.f;
#pragma unroll
  for (int i = 0; i < 8; i++) { su += x[i]; sq += x[i] * x[i]; }
#pragma unroll
  for (int off = 32; off > 0; off >>= 1) {
    su += __shfl_xor(su, off, 64);
    sq += __shfl_xor(sq, off, 64);
  }
  float mean = su * (1.f / 512.f);
  float var = sq * (1.f / 512.f) - mean * mean;
  float rs = rsqrtf(var + EPS_);
#pragma unroll
  for (int i = 0; i < 8; i++) t3[w][d + i] = (x[i] - mean) * rs * g[d + i] + be[d + i];
  __syncthreads();
  for (int dd = threadIdx.x; dd < DD; dd += 192)
    out[(size_t)b * DD + dd] = (t3[0][dd] + t3[1][dd] + t3[2][dd]) * (1.f / 3.f);
}

extern "C" void kernel_launch(void* const* d_in, const int* in_sizes, int n_in,
                              void* d_out, int out_size, void* d_ws, size_t ws_size,
                              hipStream_t stream) {
  const float* feat0 = (const float*)d_in[0];
  const float* feat1 = (const float*)d_in[1];
  const float* feat2 = (const float*)d_in[2];
  const float* pos   = (const float*)d_in[3];
  const float* w_in  = (const float*)d_in[4];
  const float* b_in  = (const float*)d_in[5];
  const float* w_out = (const float*)d_in[6];
  const float* b_out = (const float*)d_in[7];
  const float* ln1_g = (const float*)d_in[8];
  const float* ln1_b = (const float*)d_in[9];
  const float* w1    = (const float*)d_in[10];
  const float* b1    = (const float*)d_in[11];
  const float* w2    = (const float*)d_in[12];
  const float* b2    = (const float*)d_in[13];
  const float* ln2_g = (const float*)d_in[14];
  const float* ln2_b = (const float*)d_in[15];
  float* out = (float*)d_out;

  // ---- workspace carve ----
  char* p = (char*)d_ws;
  unsigned short* w_in_b  = (unsigned short*)p; p += (size_t)1536 * 512 * 2;
  unsigned short* w_out_b = (unsigned short*)p; p += (size_t)512 * 512 * 2;
  unsigned short* w1_b    = (unsigned short*)p; p += (size_t)2048 * 512 * 2;
  unsigned short* w2_b    = (unsigned short*)p; p += (size_t)512 * 2048 * 2;
  size_t wbytes = (size_t)(p - (char*)d_ws);

  // chunk count: smallest that fits ws (deterministic across calls)
  int nch = 16;
  for (int c = 1; c <= 16; c <<= 1) {
    size_t rows = (size_t)(BTOT / c) * 3;
    if (wbytes + rows * 9216 <= ws_size) { nch = c; break; }
  }
  const int Bc = BTOT / nch;
  const int rows = Bc * 3;

  unsigned short* xbf = (unsigned short*)p;            // x -> x1 (aliased in time)
  char* regB = p + (size_t)rows * 1024;                // qkv bf16 -> y' f32 -> f' f32
  unsigned short* ob = (unsigned short*)(regB + (size_t)rows * 3072);
  unsigned short* hb = ob + (size_t)rows * 512;        // h bf16 [rows,2048]

  // K0: weight casts
  cast_w<<<768, 256, 0, stream>>>(w_in, w_in_b, 1536 * 512);
  cast_w<<<256, 256, 0, stream>>>(w_out, w_out_b, 512 * 512);
  cast_w<<<1024, 256, 0, stream>>>(w1, w1_b, 2048 * 512);
  cast_w<<<1024, 256, 0, stream>>>(w2, w2_b, 512 * 2048);

  for (int c = 0; c < nch; c++) {
    int b0 = c * Bc;
    build_x<<<rows / 2, 256, 0, stream>>>(feat0, feat1, feat2, pos, xbf, b0);
    gemm_bt<0, 1, 0><<<dim3(12, rows / 128), 256, 0, stream>>>(
        xbf, w_in_b, b_in, nullptr, (void*)regB, rows, 1536, 512);
    attn_k<<<Bc, 512, 0, stream>>>((const unsigned short*)regB, ob);
    gemm_bt<0, 0, 1><<<dim3(4, rows / 128), 256, 0, stream>>>(
        ob, w_out_b, b_out, xbf, (void*)regB, rows, 512, 512);   // y' = x + o@W^T
    ln_row<<<rows / 4, 256, 0, stream>>>((const float*)regB, ln1_g, ln1_b, xbf);
    gemm_bt<1, 1, 0><<<dim3(16, rows / 128), 256, 0, stream>>>(
        xbf, w1_b, b1, nullptr, (void*)hb, rows, 2048, 512);
    gemm_bt<0, 0, 1><<<dim3(4, rows / 128), 256, 0, stream>>>(
        hb, w2_b, b2, xbf, (void*)regB, rows, 512, 2048);        // f' = x1 + h@W^T
    final_k<<<Bc, 192, 0, stream>>>((const float*)regB, ln2_g, ln2_b,
                                    out + (size_t)b0 * DD);
  }
}

// Round 4
// 663.991 us; speedup vs baseline: 1.2209x; 1.2209x over previous
//
#include <hip/hip_runtime.h>
#include <hip/hip_bf16.h>

// MultimodalFusion: B=16384, S=3, D=512, H=8, HD=64, FF=2048
// Round 4: round-2 GEMM body (BK=64 single-buffer global_load_lds, proven
// 0-conflict swizzle) + XCD-aware block swizzle; all intermediates bf16 with
// in-place aliasing so nch=1 fits (5120 B/row): 9 dispatches total.
//   K0 cast all weights fp32->bf16 (one kernel, contiguous arena)
//   K1 x = feat+pos -> bf16                         xbf [rows,512]
//   K2 GEMM qkv = x @ w_in^T + b_in -> bf16         regB stride 1536
//   K3 attention per (b,head) wave, IN-PLACE: o over q-slice of regB
//   K4 GEMM y' = x + o@w_out^T + b_out -> bf16      regB+512 (over k-slice)
//   K5 x1 = LN1(y') -> bf16                         xbf (over x; x dead)
//   K6 GEMM h = relu(x1@w1^T + b1) -> bf16          regB stride 2048 (qkv dead)
//   K7 GEMM f' = x1 + h@w2^T + b2 -> bf16           xbf IN-PLACE (epilogue
//                                                   reads x1 elem then writes)
//   K8 out[b] = mean_s LN2(f')

#define BTOT 16384
#define DD 512
#define EPS_ 1e-5f

typedef __attribute__((ext_vector_type(8))) short bf8v;
typedef __attribute__((ext_vector_type(4))) float f4v;

__device__ __forceinline__ unsigned short f2bf(float f) {
  unsigned int u = __builtin_bit_cast(unsigned int, f);
  u += 0x7fffu + ((u >> 16) & 1u);
  return (unsigned short)(u >> 16);
}
__device__ __forceinline__ float bf2f(unsigned short s) {
  unsigned int u = ((unsigned int)s) << 16;
  return __builtin_bit_cast(float, u);
}
__device__ __forceinline__ unsigned int pk2(float a, float b) {
  return (unsigned int)f2bf(a) | ((unsigned int)f2bf(b) << 16);
}
__device__ __forceinline__ void unpk8(uint4 raw, float* x) {
  x[0] = bf2f(raw.x & 0xffff); x[1] = bf2f(raw.x >> 16);
  x[2] = bf2f(raw.y & 0xffff); x[3] = bf2f(raw.y >> 16);
  x[4] = bf2f(raw.z & 0xffff); x[5] = bf2f(raw.z >> 16);
  x[6] = bf2f(raw.w & 0xffff); x[7] = bf2f(raw.w >> 16);
}

// async global->LDS, 16B per lane; lds dst is wave-uniform base + lane*16
#define GLDS16(gp, lp)                                                   \
  __builtin_amdgcn_global_load_lds(                                      \
      (const __attribute__((address_space(1))) void*)(gp),               \
      (__attribute__((address_space(3))) void*)(lp), 16, 0, 0)

// ---------------- K0: fused weight cast into contiguous bf16 arena --------
// regions (elem counts): w_in 786432 | w_out 262144 | w1 1048576 | w2 1048576
__global__ __launch_bounds__(256) void cast_all(const float* __restrict__ wi,
                                                const float* __restrict__ wo,
                                                const float* __restrict__ w1,
                                                const float* __restrict__ w2,
                                                unsigned short* __restrict__ arena) {
  int i = (blockIdx.x * 256 + threadIdx.x) * 4;
  const float* src; int off;
  if (i < 786432)       { src = wi; off = 0; }
  else if (i < 1048576) { src = wo; off = 786432; }
  else if (i < 2097152) { src = w1; off = 1048576; }
  else                  { src = w2; off = 2097152; }
  float4 v = *(const float4*)&src[i - off];
  uint2 u; u.x = pk2(v.x, v.y); u.y = pk2(v.z, v.w);
  *(uint2*)&arena[i] = u;
}

// ---------------- K1: build x = feat + pos -> bf16 ----------------
__global__ __launch_bounds__(256) void build_x(const float* __restrict__ f0,
                                               const float* __restrict__ f1,
                                               const float* __restrict__ f2,
                                               const float* __restrict__ pos,
                                               unsigned short* __restrict__ xbf, int b0) {
  int gi = blockIdx.x * 256 + threadIdx.x;
  int e = gi * 4;
  int r = e >> 9;
  int d = e & 511;
  int bl = r / 3, s = r - bl * 3;
  const float* f = (s == 0 ? f0 : (s == 1 ? f1 : f2)) + (size_t)(b0 + bl) * DD + d;
  const float* pp = pos + s * DD + d;
  float4 fv = *(const float4*)f;
  float4 pv = *(const float4*)pp;
  uint2 o; o.x = pk2(fv.x + pv.x, fv.y + pv.y); o.y = pk2(fv.z + pv.z, fv.w + pv.w);
  *(uint2*)&xbf[(size_t)r * DD + d] = o;
}

// ---------------- GEMM: C[M,N] = A[M,K] @ Bw[N,K]^T + bias (+res) ---------
// Round-2 proven body: 128x128 tile, 4 waves 2x2, wave 4x4 of 16x16x32 MFMA,
// BK=64, global_load_lds w16 staging, XOR k-chunk swizzle (0 conflicts).
// Adds: lda/ldc strides, bf16 res (stride N, may alias C elementwise),
// XCD-aware block swizzle: bid%8 = XCD; per-XCD order is col-fast over a
// row-tile so the A-tile is L2-resident across its col-tiles.
template <int ACT, int RES>
__global__ __launch_bounds__(256, 2) void gemm_bt(const unsigned short* __restrict__ A,
                                                  int lda,
                                                  const unsigned short* __restrict__ Bw,
                                                  const float* __restrict__ bias,
                                                  const unsigned short* res,
                                                  unsigned short* C, int ldc,
                                                  int N, int K) {
  __shared__ unsigned short lA[128 * 64];
  __shared__ unsigned short lB[128 * 64];
  const int tid = threadIdx.x;
  // XCD swizzle (gridDim.y divisible by 8)
  const int gx = gridDim.x;
  const int bid = blockIdx.y * gx + blockIdx.x;
  const int xcd = bid & 7;
  const int ii = bid >> 3;
  const int row0 = (xcd + 8 * (ii / gx)) * 128;
  const int col0 = (ii % gx) * 128;

  const int lane = tid & 63;
  const int w = tid >> 6;
  const int wm = (w >> 1) * 64;
  const int wn = (w & 1) * 64;
  const int lr = lane & 15;
  const int ql = lane >> 4;
  const int xk = lr & 7;

  f4v acc[4][4];
#pragma unroll
  for (int i = 0; i < 4; i++)
#pragma unroll
    for (int j = 0; j < 4; j++) acc[i][j] = (f4v)0.f;

  // staging geometry (round 2): wave w stages rows [w*32, w*32+32)
  const int c0 = w * 4;
  const int srow = lane >> 3;
  const int sq = (lane & 7) ^ srow;
  const unsigned short* Ag0 = A + (size_t)(row0 + c0 * 8 + srow) * lda + sq * 8;
  const unsigned short* Bg0 = Bw + (size_t)(col0 + c0 * 8 + srow) * K + sq * 8;
  unsigned short* lA0 = &lA[c0 * 512];
  unsigned short* lB0 = &lB[c0 * 512];

  for (int k0 = 0; k0 < K; k0 += 64) {
#pragma unroll
    for (int i = 0; i < 4; i++) {
      GLDS16(Ag0 + (size_t)(i * 8) * lda + k0, lA0 + i * 512);
      GLDS16(Bg0 + (size_t)(i * 8) * K + k0, lB0 + i * 512);
    }
    __syncthreads();
#pragma unroll
    for (int kk = 0; kk < 64; kk += 32) {
      const int slot = (((kk >> 3) + ql) ^ xk) * 8;
      bf8v af[4], bfr[4];
#pragma unroll
      for (int i = 0; i < 4; i++)
        af[i] = *(const bf8v*)&lA[(wm + i * 16 + lr) * 64 + slot];
#pragma unroll
      for (int j = 0; j < 4; j++)
        bfr[j] = *(const bf8v*)&lB[(wn + j * 16 + lr) * 64 + slot];
#pragma unroll
      for (int i = 0; i < 4; i++)
#pragma unroll
        for (int j = 0; j < 4; j++)
          acc[i][j] = __builtin_amdgcn_mfma_f32_16x16x32_bf16(af[i], bfr[j], acc[i][j], 0, 0, 0);
    }
    __syncthreads();
  }

#pragma unroll
  for (int j = 0; j < 4; j++) {
    int gcol = col0 + wn + j * 16 + lr;
    float bv = bias[gcol];
#pragma unroll
    for (int i = 0; i < 4; i++) {
#pragma unroll
      for (int r = 0; r < 4; r++) {
        int grow = row0 + wm + i * 16 + ql * 4 + r;
        float v = acc[i][j][r] + bv;
        if (RES) v += bf2f(res[(size_t)grow * N + gcol]);
        if (ACT) v = fmaxf(v, 0.f);
        C[(size_t)grow * ldc + gcol] = f2bf(v);
      }
    }
  }
}

// ---------------- K3: attention, IN-PLACE o over q-slice ----------------
// One block per batch b (8 waves = 8 heads). Each thread reads its own
// q/k/v elements into registers, then writes o to its own q positions —
// no cross-thread write/read hazard (cross-lane data moves via shfl only).
__global__ __launch_bounds__(512) void attn_k(unsigned short* __restrict__ qkv) {
  int b = blockIdx.x;
  int h = threadIdx.x >> 6;
  int lane = threadIdx.x & 63;
  size_t base = ((size_t)b * 3) * 1536 + h * 64 + lane;
  float q[3], k[3], v[3];
#pragma unroll
  for (int s = 0; s < 3; s++) {
    q[s] = bf2f(qkv[base + (size_t)s * 1536]);
    k[s] = bf2f(qkv[base + (size_t)s * 1536 + 512]);
    v[s] = bf2f(qkv[base + (size_t)s * 1536 + 1024]);
  }
  float sc[3][3];
#pragma unroll
  for (int qi = 0; qi < 3; qi++)
#pragma unroll
    for (int ki = 0; ki < 3; ki++) {
      float p = q[qi] * k[ki];
#pragma unroll
      for (int off = 32; off > 0; off >>= 1) p += __shfl_xor(p, off, 64);
      sc[qi][ki] = p * 0.125f;  // 1/sqrt(64)
    }
#pragma unroll
  for (int qi = 0; qi < 3; qi++) {
    float m = fmaxf(sc[qi][0], fmaxf(sc[qi][1], sc[qi][2]));
    float e0 = __expf(sc[qi][0] - m), e1 = __expf(sc[qi][1] - m), e2 = __expf(sc[qi][2] - m);
    float inv = 1.f / (e0 + e1 + e2);
    float o = (e0 * v[0] + e1 * v[1] + e2 * v[2]) * inv;
    qkv[base + (size_t)qi * 1536] = f2bf(o);  // o over q
  }
}

// ---------------- K5: x1 = LN(y') -> bf16; one wave per row ----------------
__global__ __launch_bounds__(256) void ln_row(const unsigned short* __restrict__ y,
                                              int ldy,
                                              const float* __restrict__ g,
                                              const float* __restrict__ be,
                                              unsigned short* __restrict__ xo) {
  int wid = threadIdx.x >> 6, lane = threadIdx.x & 63;
  size_t r = (size_t)blockIdx.x * 4 + wid;
  int d = lane * 8;
  float x[8];
  unpk8(*(const uint4*)&y[r * ldy + d], x);
  float su = 0.f, sq = 0.f;
#pragma unroll
  for (int i = 0; i < 8; i++) { su += x[i]; sq += x[i] * x[i]; }
#pragma unroll
  for (int off = 32; off > 0; off >>= 1) {
    su += __shfl_xor(su, off, 64);
    sq += __shfl_xor(sq, off, 64);
  }
  float mean = su * (1.f / 512.f);
  float var = sq * (1.f / 512.f) - mean * mean;
  float rs = rsqrtf(var + EPS_);
  unsigned short o[8];
#pragma unroll
  for (int i = 0; i < 8; i++) o[i] = f2bf((x[i] - mean) * rs * g[d + i] + be[d + i]);
  uint4 pack;
  pack.x = (unsigned)o[0] | ((unsigned)o[1] << 16);
  pack.y = (unsigned)o[2] | ((unsigned)o[3] << 16);
  pack.z = (unsigned)o[4] | ((unsigned)o[5] << 16);
  pack.w = (unsigned)o[6] | ((unsigned)o[7] << 16);
  *(uint4*)&xo[r * DD + d] = pack;
}

// ---------------- K8: out[b] = mean_s LN2(f') ----------------
__global__ __launch_bounds__(192) void final_k(const unsigned short* __restrict__ ff,
                                               const float* __restrict__ g,
                                               const float* __restrict__ be,
                                               float* __restrict__ out) {
  __shared__ float t3[3][DD];
  int w = threadIdx.x >> 6, lane = threadIdx.x & 63;
  int b = blockIdx.x;
  size_t r = (size_t)b * 3 + w;
  int d = lane * 8;
  float x[8];
  unpk8(*(const uint4*)&ff[r * DD + d], x);
  float su = 0.f, sq = 0.f;
#pragma unroll
  for (int i = 0; i < 8; i++) { su += x[i]; sq += x[i] * x[i]; }
#pragma unroll
  for (int off = 32; off > 0; off >>= 1) {
    su += __shfl_xor(su, off, 64);
    sq += __shfl_xor(sq, off, 64);
  }
  float mean = su * (1.f / 512.f);
  float var = sq * (1.f / 512.f) - mean * mean;
  float rs = rsqrtf(var + EPS_);
#pragma unroll
  for (int i = 0; i < 8; i++) t3[w][d + i] = (x[i] - mean) * rs * g[d + i] + be[d + i];
  __syncthreads();
  for (int dd = threadIdx.x; dd < DD; dd += 192)
    out[(size_t)b * DD + dd] = (t3[0][dd] + t3[1][dd] + t3[2][dd]) * (1.f / 3.f);
}

extern "C" void kernel_launch(void* const* d_in, const int* in_sizes, int n_in,
                              void* d_out, int out_size, void* d_ws, size_t ws_size,
                              hipStream_t stream) {
  const float* feat0 = (const float*)d_in[0];
  const float* feat1 = (const float*)d_in[1];
  const float* feat2 = (const float*)d_in[2];
  const float* pos   = (const float*)d_in[3];
  const float* w_in  = (const float*)d_in[4];
  const float* b_in  = (const float*)d_in[5];
  const float* w_out = (const float*)d_in[6];
  const float* b_out = (const float*)d_in[7];
  const float* ln1_g = (const float*)d_in[8];
  const float* ln1_b = (const float*)d_in[9];
  const float* w1    = (const float*)d_in[10];
  const float* b1    = (const float*)d_in[11];
  const float* w2    = (const float*)d_in[12];
  const float* b2    = (const float*)d_in[13];
  const float* ln2_g = (const float*)d_in[14];
  const float* ln2_b = (const float*)d_in[15];
  float* out = (float*)d_out;

  // ---- workspace carve: weight arena (contiguous) + per-row 5120 B ----
  unsigned short* arena  = (unsigned short*)d_ws;
  unsigned short* w_in_b  = arena;
  unsigned short* w_out_b = arena + 786432;
  unsigned short* w1_b    = arena + 1048576;
  unsigned short* w2_b    = arena + 2097152;
  char* p = (char*)d_ws + (size_t)3145728 * 2;
  const size_t wbytes = (size_t)3145728 * 2;

  int nch = 16;
  for (int c = 1; c <= 16; c <<= 1) {
    size_t rws = (size_t)(BTOT / c) * 3;
    if (wbytes + rws * 5120 <= ws_size) { nch = c; break; }
  }
  const int Bc = BTOT / nch;
  const int rows = Bc * 3;
  const int RT = rows / 128;

  unsigned short* xbf = (unsigned short*)p;                 // x -> x1 -> f'
  unsigned short* regB = xbf + (size_t)rows * 512;          // qkv/o/y' (1536) -> h (2048)

  cast_all<<<3072, 256, 0, stream>>>(w_in, w_out, w1, w2, arena);

  for (int c = 0; c < nch; c++) {
    int b0 = c * Bc;
    build_x<<<rows / 2, 256, 0, stream>>>(feat0, feat1, feat2, pos, xbf, b0);
    gemm_bt<0, 0><<<dim3(12, RT), 256, 0, stream>>>(
        xbf, 512, w_in_b, b_in, nullptr, regB, 1536, 1536, 512);
    attn_k<<<Bc, 512, 0, stream>>>(regB);
    gemm_bt<0, 1><<<dim3(4, RT), 256, 0, stream>>>(
        regB, 1536, w_out_b, b_out, xbf, regB + 512, 1536, 512, 512);  // y'
    ln_row<<<rows / 4, 256, 0, stream>>>(regB + 512, 1536, ln1_g, ln1_b, xbf);
    gemm_bt<1, 0><<<dim3(16, RT), 256, 0, stream>>>(
        xbf, 512, w1_b, b1, nullptr, regB, 2048, 2048, 512);           // h
    gemm_bt<0, 1><<<dim3(4, RT), 256, 0, stream>>>(
        regB, 2048, w2_b, b2, xbf, xbf, 512, 512, 2048);               // f' in-place
    final_k<<<Bc, 192, 0, stream>>>(xbf, ln2_g, ln2_b, out + (size_t)b0 * DD);
  }
}